// Round 1
// baseline (1491.394 us; speedup 1.0000x reference)
//
#include <hip/hip_runtime.h>

#define HW 3136
#define NN 32

typedef unsigned short ushortT;

__device__ inline float bf2f(ushortT u) {
    union { unsigned int i; float f; } v; v.i = ((unsigned int)u) << 16; return v.f;
}
__device__ inline ushortT f2bf(float f) {
    union { float f; unsigned int i; } v; v.f = f;
    unsigned int r = v.i + 0x7FFFu + ((v.i >> 16) & 1u);
    return (ushortT)(r >> 16);
}

// ---------------- GEMM1: t1[n][c][p] = sum_k w1[c][k] * x[n][k][p], C=512, K=256 ----
__global__ __launch_bounds__(256) void gemm1_k(const float* __restrict__ x,
                                               const float* __restrict__ w1,
                                               ushortT* __restrict__ t1) {
    __shared__ float wT[16][128];
    __shared__ float xT[16][64];
    const int t  = threadIdx.x;
    const int P0 = blockIdx.x * 64;
    const int C0 = blockIdx.y * 128;
    const int n  = blockIdx.z;
    const int tc = t >> 4, tp = t & 15;

    float acc[8][4];
#pragma unroll
    for (int i = 0; i < 8; i++)
#pragma unroll
        for (int j = 0; j < 4; j++) acc[i][j] = 0.f;

    const float* xbase = x + (size_t)n * 256 * HW + P0;
    const int c_l = t >> 1, kq = (t & 1) * 8;
    const int k_l = t >> 4, p4 = (t & 15) * 4;

    for (int kb = 0; kb < 256; kb += 16) {
        {   // load 128x16 weight chunk, transposed
            const float* wp = w1 + (size_t)(C0 + c_l) * 256 + kb + kq;
            float4 a = *(const float4*)wp;
            float4 b = *(const float4*)(wp + 4);
            wT[kq + 0][c_l] = a.x; wT[kq + 1][c_l] = a.y; wT[kq + 2][c_l] = a.z; wT[kq + 3][c_l] = a.w;
            wT[kq + 4][c_l] = b.x; wT[kq + 5][c_l] = b.y; wT[kq + 6][c_l] = b.z; wT[kq + 7][c_l] = b.w;
        }
        {   // load 16x64 x chunk
            float4 v = *(const float4*)(xbase + (size_t)(kb + k_l) * HW + p4);
            *(float4*)&xT[k_l][p4] = v;
        }
        __syncthreads();
#pragma unroll
        for (int kk = 0; kk < 16; kk++) {
            float4 wv0 = *(float4*)&wT[kk][tc * 8];
            float4 wv1 = *(float4*)&wT[kk][tc * 8 + 4];
            float4 xv  = *(float4*)&xT[kk][tp * 4];
            float wc[8] = {wv0.x, wv0.y, wv0.z, wv0.w, wv1.x, wv1.y, wv1.z, wv1.w};
            float xc[4] = {xv.x, xv.y, xv.z, xv.w};
#pragma unroll
            for (int i = 0; i < 8; i++)
#pragma unroll
                for (int j = 0; j < 4; j++) acc[i][j] += wc[i] * xc[j];
        }
        __syncthreads();
    }
#pragma unroll
    for (int i = 0; i < 8; i++) {
        int c = C0 + tc * 8 + i;
        ushort4 o;
        o.x = f2bf(acc[i][0]); o.y = f2bf(acc[i][1]); o.z = f2bf(acc[i][2]); o.w = f2bf(acc[i][3]);
        *(ushort4*)&t1[((size_t)n * 512 + c) * HW + P0 + tp * 4] = o;
    }
}

// ---------------- per-channel BN stats -> scale/shift -------------------------------
__global__ __launch_bounds__(256) void stats_k(const ushortT* __restrict__ tdata,
                                               const float* __restrict__ gamma,
                                               const float* __restrict__ beta,
                                               float* __restrict__ sc,
                                               float* __restrict__ sh, int C) {
    const int c = blockIdx.x, t = threadIdx.x;
    float s = 0.f, ss = 0.f;
    for (int n = 0; n < NN; n++) {
        const ushortT* src = tdata + ((size_t)n * C + c) * HW;
        for (int p = t * 4; p < HW; p += 1024) {
            ushort4 v = *(const ushort4*)(src + p);
            float a = bf2f(v.x), b = bf2f(v.y), d = bf2f(v.z), e = bf2f(v.w);
            s += a + b + d + e;
            ss += a * a + b * b + d * d + e * e;
        }
    }
#pragma unroll
    for (int off = 32; off; off >>= 1) {
        s += __shfl_down(s, off, 64);
        ss += __shfl_down(ss, off, 64);
    }
    __shared__ float rs[4], rss[4];
    if ((t & 63) == 0) { rs[t >> 6] = s; rss[t >> 6] = ss; }
    __syncthreads();
    if (t == 0) {
        float S = rs[0] + rs[1] + rs[2] + rs[3];
        float SS = rss[0] + rss[1] + rss[2] + rss[3];
        const float inv = 1.f / 100352.f;
        float m   = S * inv;
        float var = SS * inv - m * m;
        float scale = gamma[c] * rsqrtf(var + 1e-5f);
        sc[c] = scale;
        sh[c] = beta[c] - m * scale;
    }
}

// ---------------- grouped 3x3 conv with fused BN1+ReLU on input ---------------------
__global__ __launch_bounds__(256) void gconv_k(const ushortT* __restrict__ t1,
                                               const float* __restrict__ w3,
                                               const float* __restrict__ sc1,
                                               const float* __restrict__ sh1,
                                               ushortT* __restrict__ t2) {
    __shared__ float tile[16][10][72];   // row stride 72 breaks 8-way bank aliasing
    __shared__ float wlds[2304];
    const int t  = threadIdx.x;
    const int rt = blockIdx.x;   // 0..6 (8-row tiles)
    const int g  = blockIdx.y;   // 0..31
    const int n  = blockIdx.z;   // 0..31
    const int r0 = rt * 8;

    for (int idx = t; idx < 2304; idx += 256) wlds[idx] = w3[g * 2304 + idx];

    for (int ic = 0; ic < 16; ic++) {
        const int c = g * 16 + ic;
        const float s = sc1[c], h = sh1[c];
        const ushortT* src = t1 + ((size_t)n * 512 + c) * HW;
        for (int idx = t; idx < 640; idx += 256) {
            int r = idx >> 6, col = idx & 63;
            int ir = r0 - 1 + r, icol = col - 1;
            float v = 0.f;
            if (ir >= 0 && ir < 56 && icol >= 0 && icol < 56)
                v = fmaxf(fmaf(s, bf2f(src[ir * 56 + icol]), h), 0.f);
            tile[ic][r][col] = v;
        }
    }
    __syncthreads();

    const int pair = t >> 1, half = t & 1;
    const int oc = pair >> 3, r = pair & 7;
    const int c0 = half * 28;
    float4 acc[7];
#pragma unroll
    for (int j = 0; j < 7; j++) acc[j] = make_float4(0.f, 0.f, 0.f, 0.f);

    for (int ic = 0; ic < 16; ic++) {
#pragma unroll
        for (int kh = 0; kh < 3; kh++) {
            const float* wr = &wlds[(oc * 16 + ic) * 9 + kh * 3];
            const float w0 = wr[0], w1_ = wr[1], w2 = wr[2];
            const float* row = &tile[ic][r + kh][c0];
            float4 rr[8];
#pragma unroll
            for (int j = 0; j < 8; j++) rr[j] = *(const float4*)(row + 4 * j);
#pragma unroll
            for (int j = 0; j < 7; j++) {
                float4 a = rr[j], b = rr[j + 1];
                acc[j].x += w0 * a.x + w1_ * a.y + w2 * a.z;
                acc[j].y += w0 * a.y + w1_ * a.z + w2 * a.w;
                acc[j].z += w0 * a.z + w1_ * a.w + w2 * b.x;
                acc[j].w += w0 * a.w + w1_ * b.x + w2 * b.y;
            }
        }
    }
    ushortT* dst = t2 + ((size_t)n * 512 + g * 16 + oc) * HW + (r0 + r) * 56 + c0;
#pragma unroll
    for (int j = 0; j < 7; j++) {
        ushort4 o;
        o.x = f2bf(acc[j].x); o.y = f2bf(acc[j].y); o.z = f2bf(acc[j].z); o.w = f2bf(acc[j].w);
        *(ushort4*)&dst[4 * j] = o;
    }
}

// ---------------- GEMM3: t3[n][co][p] = sum_c wa[co][c]*relu(bn(t2[n][c][p])) -------
__global__ __launch_bounds__(256) void gemm3_k(const ushortT* __restrict__ t2,
                                               const float* __restrict__ wa,
                                               const float* __restrict__ sc2,
                                               const float* __restrict__ sh2,
                                               ushortT* __restrict__ t3) {
    __shared__ float wT[16][128];
    __shared__ float xT[16][64];
    const int t  = threadIdx.x;
    const int P0 = blockIdx.x * 64;
    const int C0 = blockIdx.y * 128;
    const int n  = blockIdx.z;
    const int tc = t >> 4, tp = t & 15;

    float acc[8][4];
#pragma unroll
    for (int i = 0; i < 8; i++)
#pragma unroll
        for (int j = 0; j < 4; j++) acc[i][j] = 0.f;

    const ushortT* xbase = t2 + (size_t)n * 512 * HW + P0;
    const int c_l = t >> 1, kq = (t & 1) * 8;
    const int k_l = t >> 4, p4 = (t & 15) * 4;

    for (int kb = 0; kb < 512; kb += 16) {
        {
            const float* wp = wa + (size_t)(C0 + c_l) * 512 + kb + kq;
            float4 a = *(const float4*)wp;
            float4 b = *(const float4*)(wp + 4);
            wT[kq + 0][c_l] = a.x; wT[kq + 1][c_l] = a.y; wT[kq + 2][c_l] = a.z; wT[kq + 3][c_l] = a.w;
            wT[kq + 4][c_l] = b.x; wT[kq + 5][c_l] = b.y; wT[kq + 6][c_l] = b.z; wT[kq + 7][c_l] = b.w;
        }
        {
            const int ch = kb + k_l;
            const float s = sc2[ch], h = sh2[ch];
            ushort4 v = *(const ushort4*)(xbase + (size_t)ch * HW + p4);
            xT[k_l][p4 + 0] = fmaxf(fmaf(s, bf2f(v.x), h), 0.f);
            xT[k_l][p4 + 1] = fmaxf(fmaf(s, bf2f(v.y), h), 0.f);
            xT[k_l][p4 + 2] = fmaxf(fmaf(s, bf2f(v.z), h), 0.f);
            xT[k_l][p4 + 3] = fmaxf(fmaf(s, bf2f(v.w), h), 0.f);
        }
        __syncthreads();
#pragma unroll
        for (int kk = 0; kk < 16; kk++) {
            float4 wv0 = *(float4*)&wT[kk][tc * 8];
            float4 wv1 = *(float4*)&wT[kk][tc * 8 + 4];
            float4 xv  = *(float4*)&xT[kk][tp * 4];
            float wc[8] = {wv0.x, wv0.y, wv0.z, wv0.w, wv1.x, wv1.y, wv1.z, wv1.w};
            float xc[4] = {xv.x, xv.y, xv.z, xv.w};
#pragma unroll
            for (int i = 0; i < 8; i++)
#pragma unroll
                for (int j = 0; j < 4; j++) acc[i][j] += wc[i] * xc[j];
        }
        __syncthreads();
    }
#pragma unroll
    for (int i = 0; i < 8; i++) {
        int c = C0 + tc * 8 + i;
        ushort4 o;
        o.x = f2bf(acc[i][0]); o.y = f2bf(acc[i][1]); o.z = f2bf(acc[i][2]); o.w = f2bf(acc[i][3]);
        *(ushort4*)&t3[((size_t)n * 256 + c) * HW + P0 + tp * 4] = o;
    }
}

// ---------------- final: out = relu(bn3(t3) + x) ------------------------------------
__global__ __launch_bounds__(256) void final_k(const ushortT* __restrict__ t3,
                                               const float* __restrict__ x,
                                               const float* __restrict__ sc3,
                                               const float* __restrict__ sh3,
                                               float* __restrict__ out) {
    const unsigned int i = (blockIdx.x * 256u + threadIdx.x) * 4u;
    const int c = (int)((i / HW) & 255u);
    ushort4 v = *(const ushort4*)(t3 + i);
    float4 xv = *(const float4*)(x + i);
    const float s = sc3[c], h = sh3[c];
    float4 o;
    o.x = fmaxf(fmaf(s, bf2f(v.x), h) + xv.x, 0.f);
    o.y = fmaxf(fmaf(s, bf2f(v.y), h) + xv.y, 0.f);
    o.z = fmaxf(fmaf(s, bf2f(v.z), h) + xv.z, 0.f);
    o.w = fmaxf(fmaf(s, bf2f(v.w), h) + xv.w, 0.f);
    *(float4*)(out + i) = o;
}

extern "C" void kernel_launch(void* const* d_in, const int* in_sizes, int n_in,
                              void* d_out, int out_size, void* d_ws, size_t ws_size,
                              hipStream_t stream) {
    const float* x  = (const float*)d_in[0];
    const float* w1 = (const float*)d_in[1];
    const float* g1 = (const float*)d_in[2];
    const float* b1 = (const float*)d_in[3];
    const float* w3 = (const float*)d_in[4];
    const float* g3 = (const float*)d_in[5];
    const float* b3 = (const float*)d_in[6];
    const float* wa = (const float*)d_in[7];
    const float* ga = (const float*)d_in[8];
    const float* ba = (const float*)d_in[9];
    float* out = (float*)d_out;

    char* ws = (char*)d_ws;
    // t1: 32*512*3136 bf16 = 102,760,448 B ; t2 same ; t3 aliases t1 (dead after gconv)
    ushortT* t1 = (ushortT*)ws;
    ushortT* t2 = (ushortT*)(ws + 102760448);
    ushortT* t3 = t1;
    float* sc1 = (float*)(ws + 205520896);
    float* sh1 = sc1 + 512;
    float* sc2 = sh1 + 512;
    float* sh2 = sc2 + 512;
    float* sc3 = sh2 + 512;
    float* sh3 = sc3 + 256;

    gemm1_k<<<dim3(49, 4, 32), 256, 0, stream>>>(x, w1, t1);
    stats_k<<<512, 256, 0, stream>>>(t1, g1, b1, sc1, sh1, 512);
    gconv_k<<<dim3(7, 32, 32), 256, 0, stream>>>(t1, w3, sc1, sh1, t2);
    stats_k<<<512, 256, 0, stream>>>(t2, g3, b3, sc2, sh2, 512);
    gemm3_k<<<dim3(49, 2, 32), 256, 0, stream>>>(t2, wa, sc2, sh2, t3);
    stats_k<<<256, 256, 0, stream>>>(t3, ga, ba, sc3, sh3, 256);
    final_k<<<25088, 256, 0, stream>>>(t3, x, sc3, sh3, out);
}

// Round 2
// 809.014 us; speedup vs baseline: 1.8435x; 1.8435x over previous
//
#include <hip/hip_runtime.h>

#define HW 3136
#define NPOS 100352.0f

typedef unsigned short ushortT;
typedef __attribute__((ext_vector_type(8))) short short8;
typedef __attribute__((ext_vector_type(4))) float floatx4;

__device__ inline float bf2f(ushortT u) {
    union { unsigned int i; float f; } v; v.i = ((unsigned int)u) << 16; return v.f;
}
__device__ inline ushortT f2bf(float f) {
    union { float f; unsigned int i; } v; v.f = f;
    unsigned int r = v.i + 0x7FFFu + ((v.i >> 16) & 1u);
    return (ushortT)(r >> 16);
}

// ---------- prep: convert weights to bf16 (+ w3 reswizzle), zero stat sums ----------
__global__ __launch_bounds__(256) void prep_k(const float* __restrict__ w1,
                                              const float* __restrict__ w3,
                                              const float* __restrict__ wa,
                                              ushortT* __restrict__ w1b,
                                              ushortT* __restrict__ wab,
                                              ushortT* __restrict__ w3b,
                                              float* __restrict__ sums_all) {
    int i = blockIdx.x * 256 + threadIdx.x;
    if (i < 131072) { w1b[i] = f2bf(w1[i]); wab[i] = f2bf(wa[i]); }
    if (i < 81920) {
        // w3b[g][s 0..9][oc][ic], s==9 is a zero pad (dummy MFMA half)
        int ic = i & 15, oc = (i >> 4) & 15, rest = i >> 8;
        int s = rest % 10, g = rest / 10;
        w3b[i] = (s < 9) ? f2bf(w3[(((g * 16 + oc) * 16) + ic) * 9 + s]) : (ushortT)0;
    }
    if (i < 2560) sums_all[i] = 0.f;
}

// ---------- transpose x: [n][k 256][p 3136] f32 -> xb [n][p][k] bf16 ----------------
__global__ __launch_bounds__(256) void transx_k(const float* __restrict__ x,
                                                ushortT* __restrict__ xb) {
    __shared__ float tf[64 * 65];
    const int t = threadIdx.x;
    const int p0 = blockIdx.x * 64, k0 = blockIdx.y * 64, n = blockIdx.z;
#pragma unroll
    for (int i = 0; i < 16; i++) {
        int idx = t + i * 256;
        int k = idx >> 6, p = idx & 63;
        tf[k * 65 + p] = x[((size_t)n * 256 + k0 + k) * HW + p0 + p];
    }
    __syncthreads();
#pragma unroll
    for (int i = 0; i < 2; i++) {
        int idx = t + i * 256;
        int p = idx >> 3, kq = (idx & 7) * 8;
        short8 o;
#pragma unroll
        for (int j = 0; j < 8; j++) o[j] = (short)f2bf(tf[(kq + j) * 65 + p]);
        *(short8*)&xb[((size_t)n * HW + p0 + p) * 256 + k0 + kq] = o;
    }
}

// ---------- MFMA GEMM1: t1[n][p][c] = sum_k w1b[c][k] * xb[n][p][k] -----------------
__global__ __launch_bounds__(256) void gemm1_k(const ushortT* __restrict__ xb,
                                               const ushortT* __restrict__ w1b,
                                               ushortT* __restrict__ t1) {
    __shared__ ushortT As[128 * 40];
    __shared__ ushortT Bs[128 * 40];
    const int t = threadIdx.x;
    const int P0 = blockIdx.x * 128, C0 = blockIdx.y * 128, n = blockIdx.z;
    const int w = t >> 6, lane = t & 63;
    const int mh = (w >> 1) * 64, nh = (w & 1) * 64;
    const int l15 = lane & 15, quad = lane >> 4;
    const int sr = t >> 2, skq = (t & 3) * 8;

    floatx4 acc[4][4];
#pragma unroll
    for (int a = 0; a < 4; a++)
#pragma unroll
        for (int b = 0; b < 4; b++)
#pragma unroll
            for (int e = 0; e < 4; e++) acc[a][b][e] = 0.f;

    for (int kb = 0; kb < 256; kb += 32) {
#pragma unroll
        for (int i = 0; i < 2; i++) {
            int r = sr + i * 64;
            short8 v = *(const short8*)&w1b[(size_t)(C0 + r) * 256 + kb + skq];
            *(short8*)&As[r * 40 + skq] = v;
        }
#pragma unroll
        for (int i = 0; i < 2; i++) {
            int p = sr + i * 64;
            short8 v;
            if (P0 + p < HW) {
                v = *(const short8*)&xb[((size_t)n * HW + P0 + p) * 256 + kb + skq];
            } else {
#pragma unroll
                for (int j = 0; j < 8; j++) v[j] = 0;
            }
            *(short8*)&Bs[p * 40 + skq] = v;
        }
        __syncthreads();
        short8 af[4], bf[4];
#pragma unroll
        for (int mt = 0; mt < 4; mt++)
            af[mt] = *(const short8*)&As[(mh + mt * 16 + l15) * 40 + quad * 8];
#pragma unroll
        for (int nt = 0; nt < 4; nt++)
            bf[nt] = *(const short8*)&Bs[(nh + nt * 16 + l15) * 40 + quad * 8];
#pragma unroll
        for (int mt = 0; mt < 4; mt++)
#pragma unroll
            for (int nt = 0; nt < 4; nt++)
                acc[mt][nt] = __builtin_amdgcn_mfma_f32_16x16x32_bf16(af[mt], bf[nt], acc[mt][nt], 0, 0, 0);
        __syncthreads();
    }
#pragma unroll
    for (int mt = 0; mt < 4; mt++) {
        int c = C0 + mh + mt * 16 + quad * 4;
#pragma unroll
        for (int nt = 0; nt < 4; nt++) {
            int pp = P0 + nh + nt * 16 + l15;
            if (pp < HW) {
                ushort4 o;
                o.x = f2bf(acc[mt][nt][0]); o.y = f2bf(acc[mt][nt][1]);
                o.z = f2bf(acc[mt][nt][2]); o.w = f2bf(acc[mt][nt][3]);
                *(ushort4*)&t1[((size_t)n * HW + pp) * 512 + c] = o;
            }
        }
    }
}

// ---------- stats: per-channel sum/sumsq of bf16 [n][p][C] via atomics --------------
__global__ __launch_bounds__(256) void stats_k(const ushortT* __restrict__ src, int C,
                                               float* __restrict__ sums) {
    const int t = threadIdx.x;
    const int pc = blockIdx.x, n = blockIdx.y;
    const int tpr = C >> 1;           // threads covering one row (2 ch each)
    const int rpi = 256 / tpr;        // rows per iteration
    const int c2 = (t % tpr) * 2, ro = t / tpr;
    float s0 = 0, s1 = 0, q0 = 0, q1 = 0;
    const int pbase = pc * 392;
    for (int i = 0; i < 392; i += rpi) {
        int p = pbase + i + ro;
        ushort2 v = *(const ushort2*)&src[((size_t)n * HW + p) * C + c2];
        float a = bf2f(v.x), b = bf2f(v.y);
        s0 += a; q0 += a * a; s1 += b; q1 += b * b;
    }
    atomicAdd(&sums[c2], s0);
    atomicAdd(&sums[c2 + 1], s1);
    atomicAdd(&sums[C + c2], q0);
    atomicAdd(&sums[C + c2 + 1], q1);
}

// ---------- gconv: grouped 3x3 as 5 dual-shift MFMAs, BN1+ReLU fused on input -------
__global__ __launch_bounds__(256) void gconv_k(const ushortT* __restrict__ t1,
                                               const ushortT* __restrict__ w3b,
                                               const float* __restrict__ sums1,
                                               const float* __restrict__ g1,
                                               const float* __restrict__ b1,
                                               ushortT* __restrict__ t2) {
    __shared__ ushortT tile[10 * 66 * 16];
    __shared__ float scs[16], shs[16];
    const int t = threadIdx.x;
    const int rt = blockIdx.x, g = blockIdx.y, n = blockIdx.z;
    const int r0 = rt * 8;

    if (t < 16) {
        int c = g * 16 + t;
        float m = sums1[c] * (1.f / NPOS);
        float var = sums1[512 + c] * (1.f / NPOS) - m * m;
        float sc = g1[c] * rsqrtf(var + 1e-5f);
        scs[t] = sc; shs[t] = b1[c] - m * sc;
    }
    __syncthreads();

    const int half = t & 1;
    float scv[8], shv[8];
#pragma unroll
    for (int j = 0; j < 8; j++) { scv[j] = scs[half * 8 + j]; shv[j] = shs[half * 8 + j]; }

    // stage 10 rows x 58 cols x 16ic (bn1+relu applied), zero-padded borders
    for (int idx = t; idx < 1160; idx += 256) {
        int pos = idx >> 1;                 // idx&1 == t&1 == half (256 is even)
        int row = pos / 58, col = pos - row * 58;
        int ir = r0 - 1 + row, icl = col - 1;
        short8 o;
        if (ir >= 0 && ir < 56 && icl >= 0 && icl < 56) {
            short8 v = *(const short8*)&t1[((size_t)n * HW + ir * 56 + icl) * 512 + g * 16 + half * 8];
#pragma unroll
            for (int j = 0; j < 8; j++)
                o[j] = (short)f2bf(fmaxf(fmaf(scv[j], bf2f((ushortT)v[j]), shv[j]), 0.f));
        } else {
#pragma unroll
            for (int j = 0; j < 8; j++) o[j] = 0;
        }
        *(short8*)&tile[(row * 66 + col) * 16 + half * 8] = o;
    }
    __syncthreads();

    const int w = t >> 6, lane = t & 63;
    const int l15 = lane & 15, quad = lane >> 4;
    const int qh = quad >> 1, ql = quad & 1;

    // A fragments from global (L2-resident), shift pair (2s, 2s+1), shift 9 = zeros
    short8 af[5];
    int drv[5], dcv[5];
#pragma unroll
    for (int s = 0; s < 5; s++) {
        int shift = 2 * s + qh;
        af[s] = *(const short8*)&w3b[((g * 10 + shift) * 16 + l15) * 16 + ql * 8];
        if (shift == 9) shift = 8;          // valid B address for dummy half
        drv[s] = shift / 3; dcv[s] = shift - drv[s] * 3;
    }

    const int rt4 = (w & 1) * 4;            // wave's 4-row band within the 8-row tile
    const int cb = (w >> 1) * 7;            // wave's 7 col-tiles (of 4 cols)
    const int pr = l15 >> 2, pc = l15 & 3;

    floatx4 acc[7];
#pragma unroll
    for (int ct = 0; ct < 7; ct++)
#pragma unroll
        for (int e = 0; e < 4; e++) acc[ct][e] = 0.f;

#pragma unroll
    for (int ct = 0; ct < 7; ct++) {
        int colb = (cb + ct) * 4 + pc;
#pragma unroll
        for (int s = 0; s < 5; s++) {
            int row = rt4 + pr + drv[s];
            int col = colb + dcv[s];
            short8 bfv = *(const short8*)&tile[(row * 66 + col) * 16 + ql * 8];
            acc[ct] = __builtin_amdgcn_mfma_f32_16x16x32_bf16(af[s], bfv, acc[ct], 0, 0, 0);
        }
    }
#pragma unroll
    for (int ct = 0; ct < 7; ct++) {
        int pos = (r0 + rt4 + pr) * 56 + (cb + ct) * 4 + pc;
        ushort4 o;
        o.x = f2bf(acc[ct][0]); o.y = f2bf(acc[ct][1]);
        o.z = f2bf(acc[ct][2]); o.w = f2bf(acc[ct][3]);
        *(ushort4*)&t2[((size_t)n * HW + pos) * 512 + g * 16 + quad * 4] = o;
    }
}

// ---------- bnrelu2: t2 <- relu(bn2(t2)) in place -----------------------------------
__global__ __launch_bounds__(256) void bnrelu2_k(ushortT* __restrict__ t2,
                                                 const float* __restrict__ sums2,
                                                 const float* __restrict__ g3,
                                                 const float* __restrict__ b3) {
    __shared__ float scs[512], shs[512];
    const int t = threadIdx.x;
#pragma unroll
    for (int i = 0; i < 2; i++) {
        int c = t + i * 256;
        float m = sums2[c] * (1.f / NPOS);
        float var = sums2[512 + c] * (1.f / NPOS) - m * m;
        float sc = g3[c] * rsqrtf(var + 1e-5f);
        scs[c] = sc; shs[c] = b3[c] - m * sc;
    }
    __syncthreads();
    size_t base = (size_t)blockIdx.x * 256 + t;
#pragma unroll
    for (int i = 0; i < 4; i++) {
        size_t gi = base + (size_t)i * 1605632;   // 6272*256 threads
        int c0 = ((int)(gi & 63)) * 8;
        short8 v = *(short8*)&t2[gi * 8];
        short8 o;
#pragma unroll
        for (int j = 0; j < 8; j++)
            o[j] = (short)f2bf(fmaxf(fmaf(scs[c0 + j], bf2f((ushortT)v[j]), shs[c0 + j]), 0.f));
        *(short8*)&t2[gi * 8] = o;
    }
}

// ---------- MFMA GEMM3: t3[n][p][co] = sum_c wab[co][c] * t2[n][p][c] ---------------
__global__ __launch_bounds__(256) void gemm3_k(const ushortT* __restrict__ t2,
                                               const ushortT* __restrict__ wab,
                                               ushortT* __restrict__ t3) {
    __shared__ ushortT As[128 * 40];
    __shared__ ushortT Bs[128 * 40];
    const int t = threadIdx.x;
    const int P0 = blockIdx.x * 128, C0 = blockIdx.y * 128, n = blockIdx.z;
    const int w = t >> 6, lane = t & 63;
    const int mh = (w >> 1) * 64, nh = (w & 1) * 64;
    const int l15 = lane & 15, quad = lane >> 4;
    const int sr = t >> 2, skq = (t & 3) * 8;

    floatx4 acc[4][4];
#pragma unroll
    for (int a = 0; a < 4; a++)
#pragma unroll
        for (int b = 0; b < 4; b++)
#pragma unroll
            for (int e = 0; e < 4; e++) acc[a][b][e] = 0.f;

    for (int kb = 0; kb < 512; kb += 32) {
#pragma unroll
        for (int i = 0; i < 2; i++) {
            int r = sr + i * 64;
            short8 v = *(const short8*)&wab[(size_t)(C0 + r) * 512 + kb + skq];
            *(short8*)&As[r * 40 + skq] = v;
        }
#pragma unroll
        for (int i = 0; i < 2; i++) {
            int p = sr + i * 64;
            short8 v;
            if (P0 + p < HW) {
                v = *(const short8*)&t2[((size_t)n * HW + P0 + p) * 512 + kb + skq];
            } else {
#pragma unroll
                for (int j = 0; j < 8; j++) v[j] = 0;
            }
            *(short8*)&Bs[p * 40 + skq] = v;
        }
        __syncthreads();
        short8 af[4], bf[4];
#pragma unroll
        for (int mt = 0; mt < 4; mt++)
            af[mt] = *(const short8*)&As[(mh + mt * 16 + l15) * 40 + quad * 8];
#pragma unroll
        for (int nt = 0; nt < 4; nt++)
            bf[nt] = *(const short8*)&Bs[(nh + nt * 16 + l15) * 40 + quad * 8];
#pragma unroll
        for (int mt = 0; mt < 4; mt++)
#pragma unroll
            for (int nt = 0; nt < 4; nt++)
                acc[mt][nt] = __builtin_amdgcn_mfma_f32_16x16x32_bf16(af[mt], bf[nt], acc[mt][nt], 0, 0, 0);
        __syncthreads();
    }
#pragma unroll
    for (int mt = 0; mt < 4; mt++) {
        int c = C0 + mh + mt * 16 + quad * 4;
#pragma unroll
        for (int nt = 0; nt < 4; nt++) {
            int pp = P0 + nh + nt * 16 + l15;
            if (pp < HW) {
                ushort4 o;
                o.x = f2bf(acc[mt][nt][0]); o.y = f2bf(acc[mt][nt][1]);
                o.z = f2bf(acc[mt][nt][2]); o.w = f2bf(acc[mt][nt][3]);
                *(ushort4*)&t3[((size_t)n * HW + pp) * 256 + c] = o;
            }
        }
    }
}

// ---------- final: out[n][c][p] = relu(bn3(t3[n][p][c]) + x[n][c][p]) ---------------
__global__ __launch_bounds__(256) void final_k(const ushortT* __restrict__ t3,
                                               const float* __restrict__ x,
                                               const float* __restrict__ sums3,
                                               const float* __restrict__ ga,
                                               const float* __restrict__ ba,
                                               float* __restrict__ out) {
    __shared__ float tf[64 * 65];
    __shared__ float scs[64], shs[64];
    const int t = threadIdx.x;
    const int p0 = blockIdx.x * 64, c0 = blockIdx.y * 64, n = blockIdx.z;
    if (t < 64) {
        int c = c0 + t;
        float m = sums3[c] * (1.f / NPOS);
        float var = sums3[256 + c] * (1.f / NPOS) - m * m;
        float sc = ga[c] * rsqrtf(var + 1e-5f);
        scs[t] = sc; shs[t] = ba[c] - m * sc;
    }
    __syncthreads();
#pragma unroll
    for (int i = 0; i < 4; i++) {
        int idx = t + i * 256;
        int p = idx >> 4, cq = (idx & 15) * 4;
        ushort4 v = *(const ushort4*)&t3[((size_t)n * HW + p0 + p) * 256 + c0 + cq];
        tf[(cq + 0) * 65 + p] = fmaf(scs[cq + 0], bf2f(v.x), shs[cq + 0]);
        tf[(cq + 1) * 65 + p] = fmaf(scs[cq + 1], bf2f(v.y), shs[cq + 1]);
        tf[(cq + 2) * 65 + p] = fmaf(scs[cq + 2], bf2f(v.z), shs[cq + 2]);
        tf[(cq + 3) * 65 + p] = fmaf(scs[cq + 3], bf2f(v.w), shs[cq + 3]);
    }
    __syncthreads();
#pragma unroll
    for (int i = 0; i < 4; i++) {
        int idx = t + i * 256;
        int c = idx >> 4, pq = (idx & 15) * 4;
        size_t off = ((size_t)n * 256 + c0 + c) * HW + p0 + pq;
        float4 xv = *(const float4*)&x[off];
        float4 o;
        o.x = fmaxf(tf[c * 65 + pq + 0] + xv.x, 0.f);
        o.y = fmaxf(tf[c * 65 + pq + 1] + xv.y, 0.f);
        o.z = fmaxf(tf[c * 65 + pq + 2] + xv.z, 0.f);
        o.w = fmaxf(tf[c * 65 + pq + 3] + xv.w, 0.f);
        *(float4*)&out[off] = o;
    }
}

extern "C" void kernel_launch(void* const* d_in, const int* in_sizes, int n_in,
                              void* d_out, int out_size, void* d_ws, size_t ws_size,
                              hipStream_t stream) {
    const float* x  = (const float*)d_in[0];
    const float* w1 = (const float*)d_in[1];
    const float* g1 = (const float*)d_in[2];
    const float* b1 = (const float*)d_in[3];
    const float* w3 = (const float*)d_in[4];
    const float* g3 = (const float*)d_in[5];
    const float* b3 = (const float*)d_in[6];
    const float* wa = (const float*)d_in[7];
    const float* ga = (const float*)d_in[8];
    const float* ba = (const float*)d_in[9];
    float* out = (float*)d_out;

    char* ws = (char*)d_ws;
    // Region 1 (102,760,448 B): t1, later reused as t3
    ushortT* t1 = (ushortT*)ws;
    ushortT* t3 = t1;
    // Region 2 (102,760,448 B): xb (first 51 MB), later overwritten by t2
    ushortT* xb = (ushortT*)(ws + 102760448);
    ushortT* t2 = (ushortT*)(ws + 102760448);
    ushortT* w1b = (ushortT*)(ws + 205520896);
    ushortT* wab = (ushortT*)(ws + 205783040);
    ushortT* w3b = (ushortT*)(ws + 206045184);
    float* sums_all = (float*)(ws + 206209024);
    float* sums1 = sums_all;
    float* sums2 = sums_all + 1024;
    float* sums3 = sums_all + 2048;

    prep_k<<<512, 256, 0, stream>>>(w1, w3, wa, w1b, wab, w3b, sums_all);
    transx_k<<<dim3(49, 4, 32), 256, 0, stream>>>(x, xb);
    gemm1_k<<<dim3(25, 4, 32), 256, 0, stream>>>(xb, w1b, t1);
    stats_k<<<dim3(8, 32), 256, 0, stream>>>(t1, 512, sums1);
    gconv_k<<<dim3(7, 32, 32), 256, 0, stream>>>(t1, w3b, sums1, g1, b1, t2);
    stats_k<<<dim3(8, 32), 256, 0, stream>>>(t2, 512, sums2);
    bnrelu2_k<<<6272, 256, 0, stream>>>(t2, sums2, g3, b3);
    gemm3_k<<<dim3(25, 2, 32), 256, 0, stream>>>(t2, wab, t3);
    stats_k<<<dim3(8, 32), 256, 0, stream>>>(t3, 256, sums3);
    final_k<<<dim3(49, 4, 32), 256, 0, stream>>>(t3, x, sums3, ga, ba, out);
}

// Round 3
// 598.841 us; speedup vs baseline: 2.4905x; 1.3510x over previous
//
#include <hip/hip_runtime.h>

#define HW 3136
#define NPOS 100352.0f

typedef unsigned short ushortT;
typedef __attribute__((ext_vector_type(8))) short short8;
typedef __attribute__((ext_vector_type(4))) float floatx4;

__device__ inline float bf2f(ushortT u) {
    union { unsigned int i; float f; } v; v.i = ((unsigned int)u) << 16; return v.f;
}
__device__ inline ushortT f2bf(float f) {
    union { float f; unsigned int i; } v; v.f = f;
    unsigned int r = v.i + 0x7FFFu + ((v.i >> 16) & 1u);
    return (ushortT)(r >> 16);
}

// ---------- prep: convert weights to bf16 (+ w3 reswizzle), zero stat sums ----------
__global__ __launch_bounds__(256) void prep_k(const float* __restrict__ w1,
                                              const float* __restrict__ w3,
                                              const float* __restrict__ wa,
                                              ushortT* __restrict__ w1b,
                                              ushortT* __restrict__ wab,
                                              ushortT* __restrict__ w3b,
                                              float* __restrict__ sums_all) {
    int i = blockIdx.x * 256 + threadIdx.x;
    if (i < 131072) { w1b[i] = f2bf(w1[i]); wab[i] = f2bf(wa[i]); }
    if (i < 81920) {
        // w3b[g][s 0..9][oc][ic], s==9 is a zero pad (dummy MFMA half)
        int ic = i & 15, oc = (i >> 4) & 15, rest = i >> 8;
        int s = rest % 10, g = rest / 10;
        w3b[i] = (s < 9) ? f2bf(w3[(((g * 16 + oc) * 16) + ic) * 9 + s]) : (ushortT)0;
    }
    if (i < 2560) sums_all[i] = 0.f;
}

// ---------- transpose x: [n][k 256][p 3136] f32 -> xb [n][p][k] bf16 ----------------
__global__ __launch_bounds__(256) void transx_k(const float* __restrict__ x,
                                                ushortT* __restrict__ xb) {
    __shared__ float tf[64 * 65];
    const int t = threadIdx.x;
    const int p0 = blockIdx.x * 64, k0 = blockIdx.y * 64, n = blockIdx.z;
#pragma unroll
    for (int i = 0; i < 16; i++) {
        int idx = t + i * 256;
        int k = idx >> 6, p = idx & 63;
        tf[k * 65 + p] = x[((size_t)n * 256 + k0 + k) * HW + p0 + p];
    }
    __syncthreads();
#pragma unroll
    for (int i = 0; i < 2; i++) {
        int idx = t + i * 256;
        int p = idx >> 3, kq = (idx & 7) * 8;
        short8 o;
#pragma unroll
        for (int j = 0; j < 8; j++) o[j] = (short)f2bf(tf[(kq + j) * 65 + p]);
        *(short8*)&xb[((size_t)n * HW + p0 + p) * 256 + k0 + kq] = o;
    }
}

// ---------- MFMA GEMM1: t1[n][p][c] = sum_k w1b[c][k] * xb[n][p][k] -----------------
__global__ __launch_bounds__(256) void gemm1_k(const ushortT* __restrict__ xb,
                                               const ushortT* __restrict__ w1b,
                                               ushortT* __restrict__ t1) {
    __shared__ ushortT As[128 * 40];
    __shared__ ushortT Bs[128 * 40];
    const int t = threadIdx.x;
    const int P0 = blockIdx.x * 128, C0 = blockIdx.y * 128, n = blockIdx.z;
    const int w = t >> 6, lane = t & 63;
    const int mh = (w >> 1) * 64, nh = (w & 1) * 64;
    const int l15 = lane & 15, quad = lane >> 4;
    const int sr = t >> 2, skq = (t & 3) * 8;

    floatx4 acc[4][4];
#pragma unroll
    for (int a = 0; a < 4; a++)
#pragma unroll
        for (int b = 0; b < 4; b++)
#pragma unroll
            for (int e = 0; e < 4; e++) acc[a][b][e] = 0.f;

    for (int kb = 0; kb < 256; kb += 32) {
#pragma unroll
        for (int i = 0; i < 2; i++) {
            int r = sr + i * 64;
            short8 v = *(const short8*)&w1b[(size_t)(C0 + r) * 256 + kb + skq];
            *(short8*)&As[r * 40 + skq] = v;
        }
#pragma unroll
        for (int i = 0; i < 2; i++) {
            int p = sr + i * 64;
            short8 v;
            if (P0 + p < HW) {
                v = *(const short8*)&xb[((size_t)n * HW + P0 + p) * 256 + kb + skq];
            } else {
#pragma unroll
                for (int j = 0; j < 8; j++) v[j] = 0;
            }
            *(short8*)&Bs[p * 40 + skq] = v;
        }
        __syncthreads();
        short8 af[4], bf[4];
#pragma unroll
        for (int mt = 0; mt < 4; mt++)
            af[mt] = *(const short8*)&As[(mh + mt * 16 + l15) * 40 + quad * 8];
#pragma unroll
        for (int nt = 0; nt < 4; nt++)
            bf[nt] = *(const short8*)&Bs[(nh + nt * 16 + l15) * 40 + quad * 8];
#pragma unroll
        for (int mt = 0; mt < 4; mt++)
#pragma unroll
            for (int nt = 0; nt < 4; nt++)
                acc[mt][nt] = __builtin_amdgcn_mfma_f32_16x16x32_bf16(af[mt], bf[nt], acc[mt][nt], 0, 0, 0);
        __syncthreads();
    }
#pragma unroll
    for (int mt = 0; mt < 4; mt++) {
        int c = C0 + mh + mt * 16 + quad * 4;
#pragma unroll
        for (int nt = 0; nt < 4; nt++) {
            int pp = P0 + nh + nt * 16 + l15;
            if (pp < HW) {
                ushort4 o;
                o.x = f2bf(acc[mt][nt][0]); o.y = f2bf(acc[mt][nt][1]);
                o.z = f2bf(acc[mt][nt][2]); o.w = f2bf(acc[mt][nt][3]);
                *(ushort4*)&t1[((size_t)n * HW + pp) * 512 + c] = o;
            }
        }
    }
}

// ---------- stats: per-channel sum/sumsq over flat [row][C] bf16, block-reduced -----
__global__ __launch_bounds__(256) void stats_k(const ushortT* __restrict__ src, int C,
                                               float* __restrict__ sums,
                                               int rows_per_block) {
    const int t = threadIdx.x;
    const int tpr = C >> 3;           // threads covering one row (8 ch each)
    const int rpi = 256 / tpr;        // rows per iteration
    const int c8 = (t % tpr) * 8;
    const int ro = t / tpr;
    const size_t row0 = (size_t)blockIdx.x * rows_per_block;

    float s[8], q[8];
#pragma unroll
    for (int j = 0; j < 8; j++) { s[j] = 0.f; q[j] = 0.f; }

    for (int i = 0; i < rows_per_block; i += rpi) {
        size_t r = row0 + i + ro;
        short8 v = *(const short8*)&src[r * C + c8];
#pragma unroll
        for (int j = 0; j < 8; j++) {
            float a = bf2f((ushortT)v[j]);
            s[j] += a; q[j] += a * a;
        }
    }

    __shared__ float lds[4096];
#pragma unroll
    for (int j = 0; j < 8; j++) {
        lds[t * 8 + j] = s[j];
        lds[2048 + t * 8 + j] = q[j];
    }
    __syncthreads();
    for (int c = t; c < C; c += 256) {
        float S = 0.f, Q = 0.f;
        for (int rdx = 0; rdx < rpi; rdx++) {
            int st = rdx * tpr + (c >> 3);
            S += lds[st * 8 + (c & 7)];
            Q += lds[2048 + st * 8 + (c & 7)];
        }
        atomicAdd(&sums[c], S);
        atomicAdd(&sums[C + c], Q);
    }
}

// ---------- gconv: grouped 3x3 as 5 dual-shift MFMAs, BN1+ReLU fused on input -------
__global__ __launch_bounds__(256) void gconv_k(const ushortT* __restrict__ t1,
                                               const ushortT* __restrict__ w3b,
                                               const float* __restrict__ sums1,
                                               const float* __restrict__ g1,
                                               const float* __restrict__ b1,
                                               ushortT* __restrict__ t2) {
    __shared__ ushortT tile[10 * 66 * 16];
    __shared__ float scs[16], shs[16];
    const int t = threadIdx.x;
    const int rt = blockIdx.x, g = blockIdx.y, n = blockIdx.z;
    const int r0 = rt * 8;

    if (t < 16) {
        int c = g * 16 + t;
        float m = sums1[c] * (1.f / NPOS);
        float var = sums1[512 + c] * (1.f / NPOS) - m * m;
        float sc = g1[c] * rsqrtf(var + 1e-5f);
        scs[t] = sc; shs[t] = b1[c] - m * sc;
    }
    __syncthreads();

    const int half = t & 1;
    float scv[8], shv[8];
#pragma unroll
    for (int j = 0; j < 8; j++) { scv[j] = scs[half * 8 + j]; shv[j] = shs[half * 8 + j]; }

    // stage 10 rows x 58 cols x 16ic (bn1+relu applied), zero-padded borders
    for (int idx = t; idx < 1160; idx += 256) {
        int pos = idx >> 1;                 // idx&1 == t&1 == half (256 is even)
        int row = pos / 58, col = pos - row * 58;
        int ir = r0 - 1 + row, icl = col - 1;
        short8 o;
        if (ir >= 0 && ir < 56 && icl >= 0 && icl < 56) {
            short8 v = *(const short8*)&t1[((size_t)n * HW + ir * 56 + icl) * 512 + g * 16 + half * 8];
#pragma unroll
            for (int j = 0; j < 8; j++)
                o[j] = (short)f2bf(fmaxf(fmaf(scv[j], bf2f((ushortT)v[j]), shv[j]), 0.f));
        } else {
#pragma unroll
            for (int j = 0; j < 8; j++) o[j] = 0;
        }
        *(short8*)&tile[(row * 66 + col) * 16 + half * 8] = o;
    }
    __syncthreads();

    const int w = t >> 6, lane = t & 63;
    const int l15 = lane & 15, quad = lane >> 4;
    const int qh = quad >> 1, ql = quad & 1;

    // A fragments from global (L2-resident), shift pair (2s, 2s+1), shift 9 = zeros
    short8 af[5];
    int drv[5], dcv[5];
#pragma unroll
    for (int s = 0; s < 5; s++) {
        int shift = 2 * s + qh;
        af[s] = *(const short8*)&w3b[((g * 10 + shift) * 16 + l15) * 16 + ql * 8];
        if (shift == 9) shift = 8;          // valid B address for dummy half
        drv[s] = shift / 3; dcv[s] = shift - drv[s] * 3;
    }

    const int rt4 = (w & 1) * 4;            // wave's 4-row band within the 8-row tile
    const int cb = (w >> 1) * 7;            // wave's 7 col-tiles (of 4 cols)
    const int pr = l15 >> 2, pc = l15 & 3;

    floatx4 acc[7];
#pragma unroll
    for (int ct = 0; ct < 7; ct++)
#pragma unroll
        for (int e = 0; e < 4; e++) acc[ct][e] = 0.f;

#pragma unroll
    for (int ct = 0; ct < 7; ct++) {
        int colb = (cb + ct) * 4 + pc;
#pragma unroll
        for (int s = 0; s < 5; s++) {
            int row = rt4 + pr + drv[s];
            int col = colb + dcv[s];
            short8 bfv = *(const short8*)&tile[(row * 66 + col) * 16 + ql * 8];
            acc[ct] = __builtin_amdgcn_mfma_f32_16x16x32_bf16(af[s], bfv, acc[ct], 0, 0, 0);
        }
    }
#pragma unroll
    for (int ct = 0; ct < 7; ct++) {
        int pos = (r0 + rt4 + pr) * 56 + (cb + ct) * 4 + pc;
        ushort4 o;
        o.x = f2bf(acc[ct][0]); o.y = f2bf(acc[ct][1]);
        o.z = f2bf(acc[ct][2]); o.w = f2bf(acc[ct][3]);
        *(ushort4*)&t2[((size_t)n * HW + pos) * 512 + g * 16 + quad * 4] = o;
    }
}

// ---------- bnrelu2: t2 <- relu(bn2(t2)) in place -----------------------------------
__global__ __launch_bounds__(256) void bnrelu2_k(ushortT* __restrict__ t2,
                                                 const float* __restrict__ sums2,
                                                 const float* __restrict__ g3,
                                                 const float* __restrict__ b3) {
    __shared__ float scs[512], shs[512];
    const int t = threadIdx.x;
#pragma unroll
    for (int i = 0; i < 2; i++) {
        int c = t + i * 256;
        float m = sums2[c] * (1.f / NPOS);
        float var = sums2[512 + c] * (1.f / NPOS) - m * m;
        float sc = g3[c] * rsqrtf(var + 1e-5f);
        scs[c] = sc; shs[c] = b3[c] - m * sc;
    }
    __syncthreads();
    size_t base = (size_t)blockIdx.x * 256 + t;
#pragma unroll
    for (int i = 0; i < 4; i++) {
        size_t gi = base + (size_t)i * 1605632;   // 6272*256 threads
        int c0 = ((int)(gi & 63)) * 8;
        short8 v = *(short8*)&t2[gi * 8];
        short8 o;
#pragma unroll
        for (int j = 0; j < 8; j++)
            o[j] = (short)f2bf(fmaxf(fmaf(scs[c0 + j], bf2f((ushortT)v[j]), shs[c0 + j]), 0.f));
        *(short8*)&t2[gi * 8] = o;
    }
}

// ---------- MFMA GEMM3: t3[n][p][co] = sum_c wab[co][c] * t2[n][p][c] ---------------
__global__ __launch_bounds__(256) void gemm3_k(const ushortT* __restrict__ t2,
                                               const ushortT* __restrict__ wab,
                                               ushortT* __restrict__ t3) {
    __shared__ ushortT As[128 * 40];
    __shared__ ushortT Bs[128 * 40];
    const int t = threadIdx.x;
    const int P0 = blockIdx.x * 128, C0 = blockIdx.y * 128, n = blockIdx.z;
    const int w = t >> 6, lane = t & 63;
    const int mh = (w >> 1) * 64, nh = (w & 1) * 64;
    const int l15 = lane & 15, quad = lane >> 4;
    const int sr = t >> 2, skq = (t & 3) * 8;

    floatx4 acc[4][4];
#pragma unroll
    for (int a = 0; a < 4; a++)
#pragma unroll
        for (int b = 0; b < 4; b++)
#pragma unroll
            for (int e = 0; e < 4; e++) acc[a][b][e] = 0.f;

    for (int kb = 0; kb < 512; kb += 32) {
#pragma unroll
        for (int i = 0; i < 2; i++) {
            int r = sr + i * 64;
            short8 v = *(const short8*)&wab[(size_t)(C0 + r) * 512 + kb + skq];
            *(short8*)&As[r * 40 + skq] = v;
        }
#pragma unroll
        for (int i = 0; i < 2; i++) {
            int p = sr + i * 64;
            short8 v;
            if (P0 + p < HW) {
                v = *(const short8*)&t2[((size_t)n * HW + P0 + p) * 512 + kb + skq];
            } else {
#pragma unroll
                for (int j = 0; j < 8; j++) v[j] = 0;
            }
            *(short8*)&Bs[p * 40 + skq] = v;
        }
        __syncthreads();
        short8 af[4], bf[4];
#pragma unroll
        for (int mt = 0; mt < 4; mt++)
            af[mt] = *(const short8*)&As[(mh + mt * 16 + l15) * 40 + quad * 8];
#pragma unroll
        for (int nt = 0; nt < 4; nt++)
            bf[nt] = *(const short8*)&Bs[(nh + nt * 16 + l15) * 40 + quad * 8];
#pragma unroll
        for (int mt = 0; mt < 4; mt++)
#pragma unroll
            for (int nt = 0; nt < 4; nt++)
                acc[mt][nt] = __builtin_amdgcn_mfma_f32_16x16x32_bf16(af[mt], bf[nt], acc[mt][nt], 0, 0, 0);
        __syncthreads();
    }
#pragma unroll
    for (int mt = 0; mt < 4; mt++) {
        int c = C0 + mh + mt * 16 + quad * 4;
#pragma unroll
        for (int nt = 0; nt < 4; nt++) {
            int pp = P0 + nh + nt * 16 + l15;
            if (pp < HW) {
                ushort4 o;
                o.x = f2bf(acc[mt][nt][0]); o.y = f2bf(acc[mt][nt][1]);
                o.z = f2bf(acc[mt][nt][2]); o.w = f2bf(acc[mt][nt][3]);
                *(ushort4*)&t3[((size_t)n * HW + pp) * 256 + c] = o;
            }
        }
    }
}

// ---------- final: out[n][c][p] = relu(bn3(t3[n][p][c]) + x[n][c][p]) ---------------
__global__ __launch_bounds__(256) void final_k(const ushortT* __restrict__ t3,
                                               const float* __restrict__ x,
                                               const float* __restrict__ sums3,
                                               const float* __restrict__ ga,
                                               const float* __restrict__ ba,
                                               float* __restrict__ out) {
    __shared__ float tf[64 * 65];
    __shared__ float scs[64], shs[64];
    const int t = threadIdx.x;
    const int p0 = blockIdx.x * 64, c0 = blockIdx.y * 64, n = blockIdx.z;
    if (t < 64) {
        int c = c0 + t;
        float m = sums3[c] * (1.f / NPOS);
        float var = sums3[256 + c] * (1.f / NPOS) - m * m;
        float sc = ga[c] * rsqrtf(var + 1e-5f);
        scs[t] = sc; shs[t] = ba[c] - m * sc;
    }
    __syncthreads();
#pragma unroll
    for (int i = 0; i < 4; i++) {
        int idx = t + i * 256;
        int p = idx >> 4, cq = (idx & 15) * 4;
        ushort4 v = *(const ushort4*)&t3[((size_t)n * HW + p0 + p) * 256 + c0 + cq];
        tf[(cq + 0) * 65 + p] = fmaf(scs[cq + 0], bf2f(v.x), shs[cq + 0]);
        tf[(cq + 1) * 65 + p] = fmaf(scs[cq + 1], bf2f(v.y), shs[cq + 1]);
        tf[(cq + 2) * 65 + p] = fmaf(scs[cq + 2], bf2f(v.z), shs[cq + 2]);
        tf[(cq + 3) * 65 + p] = fmaf(scs[cq + 3], bf2f(v.w), shs[cq + 3]);
    }
    __syncthreads();
#pragma unroll
    for (int i = 0; i < 4; i++) {
        int idx = t + i * 256;
        int c = idx >> 4, pq = (idx & 15) * 4;
        size_t off = ((size_t)n * 256 + c0 + c) * HW + p0 + pq;
        float4 xv = *(const float4*)&x[off];
        float4 o;
        o.x = fmaxf(tf[c * 65 + pq + 0] + xv.x, 0.f);
        o.y = fmaxf(tf[c * 65 + pq + 1] + xv.y, 0.f);
        o.z = fmaxf(tf[c * 65 + pq + 2] + xv.z, 0.f);
        o.w = fmaxf(tf[c * 65 + pq + 3] + xv.w, 0.f);
        *(float4*)&out[off] = o;
    }
}

extern "C" void kernel_launch(void* const* d_in, const int* in_sizes, int n_in,
                              void* d_out, int out_size, void* d_ws, size_t ws_size,
                              hipStream_t stream) {
    const float* x  = (const float*)d_in[0];
    const float* w1 = (const float*)d_in[1];
    const float* g1 = (const float*)d_in[2];
    const float* b1 = (const float*)d_in[3];
    const float* w3 = (const float*)d_in[4];
    const float* g3 = (const float*)d_in[5];
    const float* b3 = (const float*)d_in[6];
    const float* wa = (const float*)d_in[7];
    const float* ga = (const float*)d_in[8];
    const float* ba = (const float*)d_in[9];
    float* out = (float*)d_out;

    char* ws = (char*)d_ws;
    // Region 1 (102,760,448 B): t1, later reused as t3
    ushortT* t1 = (ushortT*)ws;
    ushortT* t3 = t1;
    // Region 2 (102,760,448 B): xb (first 51 MB), later overwritten by t2
    ushortT* xb = (ushortT*)(ws + 102760448);
    ushortT* t2 = (ushortT*)(ws + 102760448);
    ushortT* w1b = (ushortT*)(ws + 205520896);
    ushortT* wab = (ushortT*)(ws + 205783040);
    ushortT* w3b = (ushortT*)(ws + 206045184);
    float* sums_all = (float*)(ws + 206209024);
    float* sums1 = sums_all;
    float* sums2 = sums_all + 1024;
    float* sums3 = sums_all + 2048;

    prep_k<<<512, 256, 0, stream>>>(w1, w3, wa, w1b, wab, w3b, sums_all);
    transx_k<<<dim3(49, 4, 32), 256, 0, stream>>>(x, xb);
    gemm1_k<<<dim3(25, 4, 32), 256, 0, stream>>>(xb, w1b, t1);
    stats_k<<<784, 256, 0, stream>>>(t1, 512, sums1, 128);
    gconv_k<<<dim3(7, 32, 32), 256, 0, stream>>>(t1, w3b, sums1, g1, b1, t2);
    stats_k<<<784, 256, 0, stream>>>(t2, 512, sums2, 128);
    bnrelu2_k<<<6272, 256, 0, stream>>>(t2, sums2, g3, b3);
    gemm3_k<<<dim3(25, 2, 32), 256, 0, stream>>>(t2, wab, t3);
    stats_k<<<784, 256, 0, stream>>>(t3, 256, sums3, 128);
    final_k<<<dim3(49, 4, 32), 256, 0, stream>>>(t3, x, sums3, ga, ba, out);
}